// Round 5
// baseline (968.410 us; speedup 1.0000x reference)
//
#include <hip/hip_runtime.h>

// RRF2d: y[b,o,p] = sum_l patches[b,l,p] * W[o,l,p] + bias[o,p]
// B=32, C_IN=32, H=W=64, K=3 pad=1, C_OUT=64, L=4096, KL=288
//
// R5: triple-buffered weight staging (1 barrier per c), counted vmcnt(8)
// BEFORE the barrier (cross-wave DMA visibility), and register-prefetch of
// the x tap-row one dh-stage ahead (fenced with sched_barrier so the young
// vmem set is exactly the 8 prefetch loads). Edge row-masking only in the
// 2/32 boundary row-blocks.
// Block (64,4): 4 waves = 4 b-chunks => all 32 batches per block (weights
// leave HBM exactly once). Thread tile: 2 cols (float2) x 2 o x 8 b.
// Grid = 32 p-blocks (2 rows) x 32 o-blocks = 1024 blocks = 4/CU.

#define C_IN   32
#define H_SZ   64
#define W_SZ   64
#define C_OUT  64
#define L_SZ   4096
#define KL     288
#define XCH    (H_SZ * W_SZ)

__device__ __forceinline__ void gload_lds4(const float* g, float* l) {
    __builtin_amdgcn_global_load_lds(
        (const __attribute__((address_space(1))) void*)g,
        (__attribute__((address_space(3))) void*)l, 4, 0, 0);
}

__global__ __launch_bounds__(256, 4)
void rrf2d_kernel(const float* __restrict__ x,
                  const float* __restrict__ wgt,
                  const float* __restrict__ bias,
                  float* __restrict__ out) {
    __shared__ float wlds[3][9 * 2 * 128];   // [buf][(j*2+o)*128 + p_local]

    const int t   = threadIdx.x;                                  // 0..63
    const int wyu = __builtin_amdgcn_readfirstlane(threadIdx.y);  // 0..3
    const int rb  = t >> 5;
    const int k   = t & 31;
    const int c0  = k * 2;
    const int h0  = blockIdx.x * 2;
    const int o0  = blockIdx.y * 2;
    const int b0  = wyu * 8;
    const int h   = h0 + rb;
    const int p   = h * W_SZ + c0;
    const int pl  = rb * 64 + c0;
    const int p0  = h0 * W_SZ;

    int roff[3]; float rvm[3];
    #pragma unroll
    for (int dh = 0; dh < 3; ++dh) {
        const int r = h + dh - 1;
        rvm[dh] = ((unsigned)r < (unsigned)H_SZ) ? 1.f : 0.f;
        const int rc = r < 0 ? 0 : (r > H_SZ - 1 ? H_SZ - 1 : r);
        roff[dh] = rc * W_SZ + c0;
    }
    const bool topblk = (h0 == 0);
    const bool botblk = (h0 == H_SZ - 2);
    const bool lval = (k != 0), rval = (k != 31);
    const int  tl = (t == 0) ? 0 : t - 1;
    const int  tr = (t == 63) ? 63 : t + 1;

    float2 acc[8][2];
    #pragma unroll
    for (int i = 0; i < 8; ++i)
        #pragma unroll
        for (int j = 0; j < 2; ++j) { acc[i][j].x = 0.f; acc[i][j].y = 0.f; }

    const size_t obase[2] = { (size_t)o0 * (KL * (size_t)L_SZ) + p0,
                              (size_t)(o0 + 1) * (KL * (size_t)L_SZ) + p0 };

    // stage weights for channel cc into wlds[cc%3]: 9 DMA pieces per wave
    auto stage = [&](int cc) {
        float* dst = wlds[cc % 3];
        const size_t coff = (size_t)cc * 9 * L_SZ;
        #pragma unroll
        for (int s = 0; s < 9; ++s) {
            const int r = wyu * 9 + s;
            const int j = r >> 2, o = (r >> 1) & 1, q = r & 1;
            const float* g = wgt + obase[o] + coff + (size_t)j * L_SZ + q * 64 + t;
            gload_lds4(g, dst + (j * 2 + o) * 128 + q * 64);
        }
    };

    // fenced register-prefetch of tap-row (cc,dh) for all 8 b: exactly 8 loads
    auto pf = [&](int cc, int dh, float2* xn) {
        __builtin_amdgcn_sched_barrier(0);
        const float* bp = x + (size_t)cc * XCH + roff[dh];
        #pragma unroll
        for (int i = 0; i < 8; ++i)
            xn[i] = *(const float2*)(bp + (size_t)(b0 + i) * (C_IN * XCH));
        __builtin_amdgcn_sched_barrier(0);
    };

    // consume one dh tap-row: shuffle halos + 96 FMAs
    auto compute_dh = [&](int dh, const float2* xv, const float* wb, bool edge) {
        float2 wv0[3], wv1[3];
        #pragma unroll
        for (int dw = 0; dw < 3; ++dw) {
            const int j = dh * 3 + dw;
            wv0[dw] = *(const float2*)(wb + (j * 2 + 0) * 128 + pl);
            wv1[dw] = *(const float2*)(wb + (j * 2 + 1) * 128 + pl);
        }
        #pragma unroll
        for (int i = 0; i < 8; ++i) {
            float2 v = xv[i];
            if (edge) { v.x *= rvm[dh]; v.y *= rvm[dh]; }  // block-uniform guard
            const float xl0 = __shfl(v.y, tl);
            const float xr0 = __shfl(v.x, tr);
            const float xs0 = lval ? xl0 : 0.f;
            const float xs1 = v.x;
            const float xs2 = v.y;
            const float xs3 = rval ? xr0 : 0.f;
            acc[i][0].x = fmaf(xs0, wv0[0].x, acc[i][0].x);
            acc[i][0].y = fmaf(xs1, wv0[0].y, acc[i][0].y);
            acc[i][1].x = fmaf(xs0, wv1[0].x, acc[i][1].x);
            acc[i][1].y = fmaf(xs1, wv1[0].y, acc[i][1].y);
            acc[i][0].x = fmaf(xs1, wv0[1].x, acc[i][0].x);
            acc[i][0].y = fmaf(xs2, wv0[1].y, acc[i][0].y);
            acc[i][1].x = fmaf(xs1, wv1[1].x, acc[i][1].x);
            acc[i][1].y = fmaf(xs2, wv1[1].y, acc[i][1].y);
            acc[i][0].x = fmaf(xs2, wv0[2].x, acc[i][0].x);
            acc[i][0].y = fmaf(xs3, wv0[2].y, acc[i][0].y);
            acc[i][1].x = fmaf(xs2, wv1[2].x, acc[i][1].x);
            acc[i][1].y = fmaf(xs3, wv1[2].y, acc[i][1].y);
        }
    };

    float2 xx0[8], xx1[8];

    // prologue: stage c=0 weights, prefetch x(0, dh=0)
    stage(0);
    pf(0, 0, xx0);

    for (int c = 0; c < C_IN; ++c) {
        // young vmem set here = exactly the 8 pf loads (fenced) ⇒ vmcnt(8)
        // proves this wave's stage(c) DMAs drained; barrier makes it all-wave.
        __builtin_amdgcn_sched_barrier(0);
        asm volatile("s_waitcnt vmcnt(8)" ::: "memory");
        __builtin_amdgcn_s_barrier();
        __builtin_amdgcn_sched_barrier(0);

        if (c + 1 < C_IN) stage(c + 1);      // writes wlds[(c+1)%3]: idle buf

        const float* wb = wlds[c % 3];

        pf(c, 1, xx1);
        compute_dh(0, xx0, wb, topblk);
        pf(c, 2, xx0);
        compute_dh(1, xx1, wb, false);
        pf(c + 1 < C_IN ? c + 1 : c, 0, xx1);
        compute_dh(2, xx0, wb, botblk);

        #pragma unroll
        for (int i = 0; i < 8; ++i) xx0[i] = xx1[i];   // renamed away by RA
    }

    #pragma unroll
    for (int j = 0; j < 2; ++j) {
        const float2 bv = *(const float2*)(bias + (size_t)(o0 + j) * L_SZ + p);
        #pragma unroll
        for (int i = 0; i < 8; ++i) {
            float2 r;
            r.x = acc[i][j].x + bv.x;
            r.y = acc[i][j].y + bv.y;
            *(float2*)(out + ((size_t)(b0 + i) * C_OUT + (o0 + j)) * L_SZ + p) = r;
        }
    }
}

extern "C" void kernel_launch(void* const* d_in, const int* in_sizes, int n_in,
                              void* d_out, int out_size, void* d_ws, size_t ws_size,
                              hipStream_t stream) {
    const float* x    = (const float*)d_in[0];
    const float* wgt  = (const float*)d_in[1];
    const float* bias = (const float*)d_in[2];
    float* out        = (float*)d_out;

    dim3 block(64, 4);                       // 4 waves = 4 b-chunks of 8
    dim3 grid(H_SZ / 2, C_OUT / 2);          // 1024 blocks = 4/CU

    hipLaunchKernelGGL(rrf2d_kernel, grid, block, 0, stream, x, wgt, bias, out);
}

// Round 6
// 185.933 us; speedup vs baseline: 5.2084x; 5.2084x over previous
//
#include <hip/hip_runtime.h>

// RRF2d: y[b,o,p] = sum_l patches[b,l,p] * W[o,l,p] + bias[o,p]
// B=32, C_IN=32, H=W=64, K=3 pad=1, C_OUT=64, L=4096, KL=288
//
// R6 = R4 structure (known-good codegen) + CC=2 channels per staging chunk:
// half the barriers, same proven ordering (stage(next) -> vmcnt(18) ->
// barrier -> compute -> end barrier). Double-buffered LDS 2 x 18 KB = 36 KB
// => still 4 blocks/CU. Compute body identical to R4 (registers, VGPR~56).
// Block (64,4): 4 waves = 4 b-chunks => all 32 batches per block (weights
// leave HBM exactly once). Thread tile: 2 cols (float2) x 2 o x 8 b.
// Grid = 32 p-blocks (2 rows) x 32 o-blocks = 1024 blocks = 4/CU.

#define C_IN   32
#define H_SZ   64
#define W_SZ   64
#define C_OUT  64
#define L_SZ   4096
#define KL     288
#define XCH    (H_SZ * W_SZ)
#define CC     2                    // channels per chunk
#define NCHUNK (C_IN / CC)          // 16
#define WBUF   (CC * 9 * 2 * 128)   // 4608 floats = 18 KB per buffer

__device__ __forceinline__ void gload_lds4(const float* g, float* l) {
    __builtin_amdgcn_global_load_lds(
        (const __attribute__((address_space(1))) void*)g,
        (__attribute__((address_space(3))) void*)l, 4, 0, 0);
}

__global__ __launch_bounds__(256, 4)
void rrf2d_kernel(const float* __restrict__ x,
                  const float* __restrict__ wgt,
                  const float* __restrict__ bias,
                  float* __restrict__ out) {
    __shared__ float wlds[2][WBUF];          // 36 KB

    const int t   = threadIdx.x;                                  // 0..63
    const int wyu = __builtin_amdgcn_readfirstlane(threadIdx.y);  // 0..3
    const int rb  = t >> 5;
    const int k   = t & 31;
    const int c0  = k * 2;
    const int h0  = blockIdx.x * 2;
    const int o0  = blockIdx.y * 2;
    const int b0  = wyu * 8;
    const int h   = h0 + rb;
    const int p   = h * W_SZ + c0;
    const int pl  = rb * 64 + c0;            // p_local (0..127)
    const int p0  = h0 * W_SZ;

    int roff[3]; float rvm[3];
    #pragma unroll
    for (int dh = 0; dh < 3; ++dh) {
        const int r = h + dh - 1;
        rvm[dh] = ((unsigned)r < (unsigned)H_SZ) ? 1.f : 0.f;
        const int rc = r < 0 ? 0 : (r > H_SZ - 1 ? H_SZ - 1 : r);
        roff[dh] = rc * W_SZ + c0;
    }
    const bool lval = (k != 0), rval = (k != 31);
    const int  tl = (t == 0) ? 0 : t - 1;
    const int  tr = (t == 63) ? 63 : t + 1;

    float2 acc[8][2];
    #pragma unroll
    for (int i = 0; i < 8; ++i)
        #pragma unroll
        for (int j = 0; j < 2; ++j) { acc[i][j].x = 0.f; acc[i][j].y = 0.f; }

    const size_t obase[2] = { (size_t)o0 * (KL * (size_t)L_SZ) + p0,
                              (size_t)(o0 + 1) * (KL * (size_t)L_SZ) + p0 };

    // stage chunk ch (channels ch*2, ch*2+1) into wlds[ch&1].
    // 72 pieces of 64 floats; this wave's 18: r = wyu*18 + s.
    // r -> cc = r/36, rem = r%36, j = rem>>2, o = (rem>>1)&1, q = rem&1.
    // LDS dest uniform per (wyu,s) as global_load_lds requires.
    auto stage = [&](int ch) {
        float* dst = wlds[ch & 1];
        const size_t coff = (size_t)ch * (CC * 9) * L_SZ;
        #pragma unroll
        for (int s = 0; s < 18; ++s) {
            const int r  = wyu * 18 + s;
            const int cc = r / 36, rem = r % 36;
            const int j  = rem >> 2, o = (rem >> 1) & 1, q = rem & 1;
            const float* g = wgt + obase[o] + coff
                           + (size_t)(cc * 9 + j) * L_SZ + q * 64 + t;
            gload_lds4(g, dst + ((cc * 9 + j) * 2 + o) * 128 + q * 64);
        }
    };

    // prologue
    stage(0);
    asm volatile("s_waitcnt vmcnt(0)" ::: "memory");
    __builtin_amdgcn_s_barrier();

    for (int ch = 0; ch < NCHUNK; ++ch) {
        // prefetch next chunk; counted wait proves THIS wave's stage(ch)
        // drained (its DMAs are older than the 18 just issued); barrier
        // makes completion all-wave.
        if (ch + 1 < NCHUNK) {
            stage(ch + 1);
            asm volatile("s_waitcnt vmcnt(18)" ::: "memory");
        } else {
            asm volatile("s_waitcnt vmcnt(0)" ::: "memory");
        }
        __builtin_amdgcn_s_barrier();

        const float* wbc = wlds[ch & 1];

        #pragma unroll
        for (int cc = 0; cc < CC; ++cc) {
            const int c = ch * CC + cc;
            const float* wb  = wbc + cc * (9 * 2 * 128);
            const float* xco = x + (size_t)c * XCH;

            #pragma unroll
            for (int dh = 0; dh < 3; ++dh) {
                float2 wv[3][2];
                #pragma unroll
                for (int dw = 0; dw < 3; ++dw) {
                    const int j = dh * 3 + dw;
                    wv[dw][0] = *(const float2*)(wb + (j * 2 + 0) * 128 + pl);
                    wv[dw][1] = *(const float2*)(wb + (j * 2 + 1) * 128 + pl);
                }

                float xs[8][4];
                #pragma unroll
                for (int i = 0; i < 8; ++i) {
                    const float* xr_ = xco + ((size_t)(b0 + i) * C_IN) * XCH + roff[dh];
                    float2 v = *(const float2*)xr_;
                    v.x *= rvm[dh];
                    v.y *= rvm[dh];
                    const float xl = __shfl(v.y, tl);
                    const float xr = __shfl(v.x, tr);
                    xs[i][0] = lval ? xl : 0.f;
                    xs[i][1] = v.x;
                    xs[i][2] = v.y;
                    xs[i][3] = rval ? xr : 0.f;
                }

                #pragma unroll
                for (int i = 0; i < 8; ++i)
                    #pragma unroll
                    for (int dw = 0; dw < 3; ++dw) {
                        acc[i][0].x = fmaf(xs[i][dw],     wv[dw][0].x, acc[i][0].x);
                        acc[i][0].y = fmaf(xs[i][dw + 1], wv[dw][0].y, acc[i][0].y);
                        acc[i][1].x = fmaf(xs[i][dw],     wv[dw][1].x, acc[i][1].x);
                        acc[i][1].y = fmaf(xs[i][dw + 1], wv[dw][1].y, acc[i][1].y);
                    }
            }
        }
        __builtin_amdgcn_s_barrier();   // reads of wlds[ch&1] done before overwrite
    }

    #pragma unroll
    for (int j = 0; j < 2; ++j) {
        const float2 bv = *(const float2*)(bias + (size_t)(o0 + j) * L_SZ + p);
        #pragma unroll
        for (int i = 0; i < 8; ++i) {
            float2 r;
            r.x = acc[i][j].x + bv.x;
            r.y = acc[i][j].y + bv.y;
            *(float2*)(out + ((size_t)(b0 + i) * C_OUT + (o0 + j)) * L_SZ + p) = r;
        }
    }
}

extern "C" void kernel_launch(void* const* d_in, const int* in_sizes, int n_in,
                              void* d_out, int out_size, void* d_ws, size_t ws_size,
                              hipStream_t stream) {
    const float* x    = (const float*)d_in[0];
    const float* wgt  = (const float*)d_in[1];
    const float* bias = (const float*)d_in[2];
    float* out        = (float*)d_out;

    dim3 block(64, 4);                       // 4 waves = 4 b-chunks of 8
    dim3 grid(H_SZ / 2, C_OUT / 2);          // 1024 blocks = 4/CU

    hipLaunchKernelGGL(rrf2d_kernel, grid, block, 0, stream, x, wgt, bias, out);
}